// Round 13
// baseline (93.085 us; speedup 1.0000x reference)
//
#include <hip/hip_runtime.h>
#include <math.h>

#define D      2048
#define KSEL   256
#define NT     256          // threads per block; NT*8 == D
#define NBINS  512          // bins of width 1/64 over |z| in [0,8)
#define ROWS   8            // rows per block -> grid 2048 = 8 blocks/CU resident

typedef float f4 __attribute__((ext_vector_type(4)));
typedef int   i4 __attribute__((ext_vector_type(4)));

// tanh-form GELU: x * sigmoid(1.5957691*x + 0.0713548*x^3)
__device__ __forceinline__ float fast_gelu(float x) {
    float x2 = x * x;
    float t  = fmaf(x2, -0.0713548162f, -1.5957691216f);
    float e  = __expf(x * t);
    return x * __builtin_amdgcn_rcpf(1.0f + e);
}

// ---- DPP cross-lane (VALU pipe, no LDS) ----
template<int CTRL, int RMASK>
__device__ __forceinline__ float dpp_mov_f(float v) {
    int r = __builtin_amdgcn_update_dpp(0, __builtin_bit_cast(int, v),
                                        CTRL, RMASK, 0xf, true);
    return __builtin_bit_cast(float, r);
}
template<int CTRL, int RMASK>
__device__ __forceinline__ int dpp_mov_i(int v) {
    return __builtin_amdgcn_update_dpp(0, v, CTRL, RMASK, 0xf, true);
}
// inclusive prefix-sum across 64 lanes; lane 63 ends with the wave total
__device__ __forceinline__ float wave_scan_f(float x) {
    x += dpp_mov_f<0x111, 0xf>(x);   // row_shr:1
    x += dpp_mov_f<0x112, 0xf>(x);   // row_shr:2
    x += dpp_mov_f<0x114, 0xf>(x);   // row_shr:4
    x += dpp_mov_f<0x118, 0xf>(x);   // row_shr:8
    x += dpp_mov_f<0x142, 0xa>(x);   // row_bcast:15 -> rows 1,3
    x += dpp_mov_f<0x143, 0xc>(x);   // row_bcast:31 -> rows 2,3
    return x;
}
__device__ __forceinline__ int wave_scan_i(int x) {
    x += dpp_mov_i<0x111, 0xf>(x);
    x += dpp_mov_i<0x112, 0xf>(x);
    x += dpp_mov_i<0x114, 0xf>(x);
    x += dpp_mov_i<0x118, 0xf>(x);
    x += dpp_mov_i<0x142, 0xa>(x);
    x += dpp_mov_i<0x143, 0xc>(x);
    return x;
}
__device__ __forceinline__ float wave_bcast63_f(float x) {
    int r = __builtin_amdgcn_readlane(__builtin_bit_cast(int, x), 63);
    return __builtin_bit_cast(float, r);
}

// Fused; persistent-resident grid; 2 barriers/row; wave0 epilogue.
__global__ __launch_bounds__(NT, 8) void row_kernel(
    const float* __restrict__ x,
    const float* __restrict__ ema_mean,
    const float* __restrict__ ema_sq,
    const float* __restrict__ ema_out,
    const float* __restrict__ p_log_tau,
    const float* __restrict__ p_log_sigma,
    const float* __restrict__ p_log_w,
    float* __restrict__ out)
{
    __shared__ int   hist[2][NBINS];      // ping-pong by row parity, REVERSED
    __shared__ float ssred[4];
    __shared__ float red[2][4][2];        // per-parity dot/nrm partials
    __shared__ float gate_sh[2];

    const int t    = threadIdx.x;
    const int wave = t >> 6;
    const int lane = t & 63;

    // scalar gate params (uniform; cheap redundant compute per block)
    const float tau   = __expf(p_log_tau[0]);
    const float sigma = __logf(1.0f + __expf(p_log_sigma[0])) + 0.01f;
    const float w     = __logf(1.0f + __expf(p_log_w[0]));

    // ---- inline "prep": per-thread channel constants (once per block) ----
    f4 m0 = ((const f4*)ema_mean)[t];
    f4 m1 = ((const f4*)ema_mean)[t + NT];
    f4 q0 = ((const f4*)ema_sq)[t];
    f4 q1 = ((const f4*)ema_sq)[t + NT];
    f4 e0 = ((const f4*)ema_out)[t];
    f4 e1 = ((const f4*)ema_out)[t + NT];

    const float mv[8] = {m0.x,m0.y,m0.z,m0.w, m1.x,m1.y,m1.z,m1.w};
    const float qv[8] = {q0.x,q0.y,q0.z,q0.w, q1.x,q1.y,q1.z,q1.w};
    const float ev[8] = {e0.x,e0.y,e0.z,e0.w, e1.x,e1.y,e1.z,e1.w};

    float a_[8], b_[8];
    float ss = 0.f;
#pragma unroll
    for (int j = 0; j < 8; ++j) {
        float v = fmaxf(fmaf(-mv[j], mv[j], qv[j]), 1e-6f);
        a_[j] = 64.0f * __builtin_amdgcn_rsqf(v);     // 64/std
        b_[j] = -mv[j] * a_[j];
        ss = fmaf(ev[j], ev[j], ss);
    }
    ss = wave_scan_f(ss);
    if (lane == 63) ssred[wave] = ss;

    const size_t row0 = (size_t)blockIdx.x * ROWS;
    f4 xa = ((const f4*)(x + row0 * D))[t];
    f4 xb = ((const f4*)(x + row0 * D))[t + NT];

    hist[0][t] = 0;  hist[0][t + NT] = 0;
    hist[1][t] = 0;  hist[1][t + NT] = 0;
    __syncthreads();                       // B0: zeros + ssred visible

    const float inv_nrm =
        1.0f / (sqrtf(ssred[0] + ssred[1] + ssred[2] + ssred[3]) + 1e-8f);
    float u_[8];
#pragma unroll
    for (int j = 0; j < 8; ++j) u_[j] = ev[j] * inv_nrm;

    for (int r = 0; r < ROWS; ++r) {
        const int p = r & 1;

        // issue next row's loads FIRST — full row of work hides HBM latency
        f4 nxa, nxb;
        if (r + 1 < ROWS) {
            const float* xn = x + (row0 + r + 1) * D;
            nxa = ((const f4*)xn)[t];
            nxb = ((const f4*)xn)[t + NT];
        }

        const float xv[8] = {xa.x,xa.y,xa.z,xa.w, xb.x,xb.y,xb.z,xb.w};
        float g[8], av[8];
        float dot = 0.f, nrm = 0.f;
#pragma unroll
        for (int j = 0; j < 8; ++j) {
            float gg = fast_gelu(xv[j]);
            g[j] = gg;
            av[j] = fabsf(fmaf(xv[j], a_[j], b_[j]));   // 64*|z|
            dot = fmaf(gg, u_[j], dot);
            nrm = fmaf(gg, gg, nrm);
        }

        // cross-lane reduce dot/nrm on VALU; overlaps DS atomics below
        dot = wave_scan_f(dot);
        nrm = wave_scan_f(nrm);
        if (lane == 63) { red[p][wave][0] = dot; red[p][wave][1] = nrm; }

        // reversed-bin histogram into parity buffer
#pragma unroll
        for (int j = 0; j < 8; ++j) {
            int bin = (int)av[j];
            bin = bin > NBINS - 1 ? NBINS - 1 : bin;
            atomicAdd(&hist[p][(NBINS - 1) - bin], 1);
        }
        __syncthreads();                   // B1: hist[p] + red[p] ready

        if (wave == 0) {
            // ---- weighted scan -> topk_sum -> full gate (wave0 only) ----
            i4 va = *(const i4*)&hist[p][8 * lane];
            i4 vb = *(const i4*)&hist[p][8 * lane + 4];
            const float base = 511.5f - (float)(8 * lane);
            int c0 = va.x;
            int c1 = c0 + va.y;
            int c2 = c1 + va.z;
            int c3 = c2 + va.w;
            int c4 = c3 + vb.x;
            int c5 = c4 + vb.y;
            int c6 = c5 + vb.z;
            int c7 = c6 + vb.w;
            float w0 = (float)va.x * base;
            float w1 = fmaf((float)va.y, base - 1.0f, w0);
            float w2 = fmaf((float)va.z, base - 2.0f, w1);
            float w3 = fmaf((float)va.w, base - 3.0f, w2);
            float w4 = fmaf((float)vb.x, base - 4.0f, w3);
            float w5 = fmaf((float)vb.y, base - 5.0f, w4);
            float w6 = fmaf((float)vb.z, base - 6.0f, w5);
            float w7 = fmaf((float)vb.w, base - 7.0f, w6);

            int   incl  = wave_scan_i(c7);
            int   excl  = incl - c7;       // counts in (value-)higher bins
            float winc  = wave_scan_f(w7);
            float wexcl = winc - w7;       // their midpoint-weighted sum

            float ts = 0.f;
            {
                const int   pre[8]  = {0, c0, c1, c2, c3, c4, c5, c6};
                const int   cum[8]  = {c0, c1, c2, c3, c4, c5, c6, c7};
                const float wpre[8] = {0.f, w0, w1, w2, w3, w4, w5, w6};
#pragma unroll
                for (int k = 0; k < 8; ++k) {
                    int s0  = excl + pre[k];
                    int e0x = excl + cum[k];
                    if (s0 < KSEL && e0x >= KSEL)   // exactly one lane/k fires
                        ts = fmaf((float)(KSEL - s0), base - (float)k,
                                  wexcl + wpre[k]);
                }
            }
            ts = wave_bcast63_f(wave_scan_f(ts));

            float dd = red[p][0][0] + red[p][1][0] + red[p][2][0] + red[p][3][0];
            float nn = red[p][0][1] + red[p][1][1] + red[p][2][1] + red[p][3][1];

            const float topk_mean = ts * (1.0f / (64.0f * KSEL));
            const float cosv = dd * __builtin_amdgcn_rsqf(fmaxf(nn, 1e-24f));
            const float yt = sigma * topk_mean;
            const float et = __expf(-2.0f * yt);
            const float th = (1.0f - et) * __builtin_amdgcn_rcpf(1.0f + et);
            const float gate = __expf(-tau * cosv) * fmaf(w, th, 1.0f);
            if (lane == 0) gate_sh[p] = gate;
        } else {
            // idle waves rezero the OTHER parity buffer for row r+1
            // (its last readers finished before B2 of row r-1 < B1 of row r)
            if (t - 64 < NBINS / 4) {      // waves 1-3: 192 threads cover 512 ints
                i4 z = (i4)0;
                ((i4*)&hist[p ^ 1][0])[t - 64] = z;
            }
        }
        __syncthreads();                   // B2: gate + rezero visible

        const float gate = gate_sh[p];
        f4 oa, ob;
        oa.x = g[0]*gate; oa.y = g[1]*gate; oa.z = g[2]*gate; oa.w = g[3]*gate;
        ob.x = g[4]*gate; ob.y = g[5]*gate; ob.z = g[6]*gate; ob.w = g[7]*gate;
        f4* outr = (f4*)(out + (row0 + r) * D);
        outr[t]      = oa;
        outr[t + NT] = ob;

        xa = nxa; xb = nxb;
    }
}

extern "C" void kernel_launch(void* const* d_in, const int* in_sizes, int n_in,
                              void* d_out, int out_size, void* d_ws, size_t ws_size,
                              hipStream_t stream) {
    (void)n_in; (void)out_size; (void)d_ws; (void)ws_size;
    const float* x         = (const float*)d_in[0];
    const float* ema_mean  = (const float*)d_in[1];
    const float* ema_sq    = (const float*)d_in[2];
    const float* ema_out   = (const float*)d_in[3];
    const float* log_tau   = (const float*)d_in[4];
    const float* log_sigma = (const float*)d_in[5];
    const float* log_w     = (const float*)d_in[6];
    float* out = (float*)d_out;

    const int rows = in_sizes[0] / D;   // B*T = 16384
    row_kernel<<<rows / ROWS, NT, 0, stream>>>(x, ema_mean, ema_sq, ema_out,
                                               log_tau, log_sigma, log_w, out);
}

// Round 14
// 47.423 us; speedup vs baseline: 1.9628x; 1.9628x over previous
//
#include <hip/hip_runtime.h>
#include <math.h>

#define D      2048
#define KSEL   256
#define NT     256          // threads per block; NT*8 == D
#define NBINS  512          // bins of width 1/64 over |z| in [0,8)
#define ROWS   4            // rows per block (ping-pong hist by parity)

typedef float f4 __attribute__((ext_vector_type(4)));
typedef int   i4 __attribute__((ext_vector_type(4)));

// tanh-form GELU: x * sigmoid(1.5957691*x + 0.0713548*x^3)
__device__ __forceinline__ float fast_gelu(float x) {
    float x2 = x * x;
    float t  = fmaf(x2, -0.0713548162f, -1.5957691216f);
    float e  = __expf(x * t);
    return x * __builtin_amdgcn_rcpf(1.0f + e);
}

// ---- DPP cross-lane (VALU pipe, no LDS) ----
template<int CTRL, int RMASK>
__device__ __forceinline__ float dpp_mov_f(float v) {
    int r = __builtin_amdgcn_update_dpp(0, __builtin_bit_cast(int, v),
                                        CTRL, RMASK, 0xf, true);
    return __builtin_bit_cast(float, r);
}
template<int CTRL, int RMASK>
__device__ __forceinline__ int dpp_mov_i(int v) {
    return __builtin_amdgcn_update_dpp(0, v, CTRL, RMASK, 0xf, true);
}
// inclusive prefix-sum across 64 lanes; lane 63 ends with the wave total
__device__ __forceinline__ float wave_scan_f(float x) {
    x += dpp_mov_f<0x111, 0xf>(x);   // row_shr:1
    x += dpp_mov_f<0x112, 0xf>(x);   // row_shr:2
    x += dpp_mov_f<0x114, 0xf>(x);   // row_shr:4
    x += dpp_mov_f<0x118, 0xf>(x);   // row_shr:8
    x += dpp_mov_f<0x142, 0xa>(x);   // row_bcast:15 -> rows 1,3
    x += dpp_mov_f<0x143, 0xc>(x);   // row_bcast:31 -> rows 2,3
    return x;
}
__device__ __forceinline__ int wave_scan_i(int x) {
    x += dpp_mov_i<0x111, 0xf>(x);
    x += dpp_mov_i<0x112, 0xf>(x);
    x += dpp_mov_i<0x114, 0xf>(x);
    x += dpp_mov_i<0x118, 0xf>(x);
    x += dpp_mov_i<0x142, 0xa>(x);
    x += dpp_mov_i<0x143, 0xc>(x);
    return x;
}
__device__ __forceinline__ float wave_bcast63_f(float x) {
    int r = __builtin_amdgcn_readlane(__builtin_bit_cast(int, x), 63);
    return __builtin_bit_cast(float, r);
}

// Fused; 2 barriers per row; epilogue entirely in wave0.
__global__ __launch_bounds__(NT) void row_kernel(
    const float* __restrict__ x,
    const float* __restrict__ ema_mean,
    const float* __restrict__ ema_sq,
    const float* __restrict__ ema_out,
    const float* __restrict__ p_log_tau,
    const float* __restrict__ p_log_sigma,
    const float* __restrict__ p_log_w,
    float* __restrict__ out)
{
    __shared__ int   hist[2][NBINS];      // ping-pong by row parity, REVERSED
    __shared__ float ssred[4];
    __shared__ float red[2][4][2];        // per-parity dot/nrm partials
    __shared__ float gate_sh[2];

    const int t    = threadIdx.x;
    const int wave = t >> 6;
    const int lane = t & 63;

    // scalar gate params (uniform; cheap redundant compute per block)
    const float tau   = __expf(p_log_tau[0]);
    const float sigma = __logf(1.0f + __expf(p_log_sigma[0])) + 0.01f;
    const float w     = __logf(1.0f + __expf(p_log_w[0]));

    // ---- inline "prep": per-thread channel constants (once per block) ----
    f4 m0 = ((const f4*)ema_mean)[t];
    f4 m1 = ((const f4*)ema_mean)[t + NT];
    f4 q0 = ((const f4*)ema_sq)[t];
    f4 q1 = ((const f4*)ema_sq)[t + NT];
    f4 e0 = ((const f4*)ema_out)[t];
    f4 e1 = ((const f4*)ema_out)[t + NT];

    const float mv[8] = {m0.x,m0.y,m0.z,m0.w, m1.x,m1.y,m1.z,m1.w};
    const float qv[8] = {q0.x,q0.y,q0.z,q0.w, q1.x,q1.y,q1.z,q1.w};
    const float ev[8] = {e0.x,e0.y,e0.z,e0.w, e1.x,e1.y,e1.z,e1.w};

    float a_[8], b_[8];
    float ss = 0.f;
#pragma unroll
    for (int j = 0; j < 8; ++j) {
        float v = fmaxf(fmaf(-mv[j], mv[j], qv[j]), 1e-6f);
        a_[j] = 64.0f * __builtin_amdgcn_rsqf(v);     // 64/std
        b_[j] = -mv[j] * a_[j];
        ss = fmaf(ev[j], ev[j], ss);
    }
    ss = wave_scan_f(ss);
    if (lane == 63) ssred[wave] = ss;

    const size_t row0 = (size_t)blockIdx.x * ROWS;
    f4 xa = ((const f4*)(x + row0 * D))[t];
    f4 xb = ((const f4*)(x + row0 * D))[t + NT];

    hist[0][t] = 0;  hist[0][t + NT] = 0;
    hist[1][t] = 0;  hist[1][t + NT] = 0;
    __syncthreads();                       // B0: zeros + ssred visible

    const float inv_nrm =
        1.0f / (sqrtf(ssred[0] + ssred[1] + ssred[2] + ssred[3]) + 1e-8f);
    float u_[8];
#pragma unroll
    for (int j = 0; j < 8; ++j) u_[j] = ev[j] * inv_nrm;

#pragma unroll
    for (int r = 0; r < ROWS; ++r) {
        const int p = r & 1;
        const float xv[8] = {xa.x,xa.y,xa.z,xa.w, xb.x,xb.y,xb.z,xb.w};

        float g[8], av[8];
        float dot = 0.f, nrm = 0.f;
#pragma unroll
        for (int j = 0; j < 8; ++j) {
            float gg = fast_gelu(xv[j]);
            g[j] = gg;
            av[j] = fabsf(fmaf(xv[j], a_[j], b_[j]));   // 64*|z|
            dot = fmaf(gg, u_[j], dot);
            nrm = fmaf(gg, gg, nrm);
        }

        // prefetch next row's x (issued after compute, before atomics)
        if (r + 1 < ROWS) {
            const float* xn = x + (row0 + r + 1) * D;
            xa = ((const f4*)xn)[t];
            xb = ((const f4*)xn)[t + NT];
        }

        // cross-lane reduce dot/nrm on VALU; overlaps DS atomics below
        dot = wave_scan_f(dot);
        nrm = wave_scan_f(nrm);
        if (lane == 63) { red[p][wave][0] = dot; red[p][wave][1] = nrm; }

        // reversed-bin histogram into parity buffer
#pragma unroll
        for (int j = 0; j < 8; ++j) {
            int bin = (int)av[j];
            bin = bin > NBINS - 1 ? NBINS - 1 : bin;
            atomicAdd(&hist[p][(NBINS - 1) - bin], 1);
        }
        __syncthreads();                   // B1: hist[p] + red[p] ready

        if (wave == 0) {
            // ---- weighted scan -> topk_sum -> full gate (wave0 only) ----
            i4 va = *(const i4*)&hist[p][8 * lane];
            i4 vb = *(const i4*)&hist[p][8 * lane + 4];
            const float base = 511.5f - (float)(8 * lane);
            int c0 = va.x;
            int c1 = c0 + va.y;
            int c2 = c1 + va.z;
            int c3 = c2 + va.w;
            int c4 = c3 + vb.x;
            int c5 = c4 + vb.y;
            int c6 = c5 + vb.z;
            int c7 = c6 + vb.w;
            float w0 = (float)va.x * base;
            float w1 = fmaf((float)va.y, base - 1.0f, w0);
            float w2 = fmaf((float)va.z, base - 2.0f, w1);
            float w3 = fmaf((float)va.w, base - 3.0f, w2);
            float w4 = fmaf((float)vb.x, base - 4.0f, w3);
            float w5 = fmaf((float)vb.y, base - 5.0f, w4);
            float w6 = fmaf((float)vb.z, base - 6.0f, w5);
            float w7 = fmaf((float)vb.w, base - 7.0f, w6);

            int   incl  = wave_scan_i(c7);
            int   excl  = incl - c7;       // counts in (value-)higher bins
            float winc  = wave_scan_f(w7);
            float wexcl = winc - w7;       // their midpoint-weighted sum

            float ts = 0.f;
            {
                const int   pre[8]  = {0, c0, c1, c2, c3, c4, c5, c6};
                const int   cum[8]  = {c0, c1, c2, c3, c4, c5, c6, c7};
                const float wpre[8] = {0.f, w0, w1, w2, w3, w4, w5, w6};
#pragma unroll
                for (int k = 0; k < 8; ++k) {
                    int s0  = excl + pre[k];
                    int e0x = excl + cum[k];
                    if (s0 < KSEL && e0x >= KSEL)   // exactly one lane/k fires
                        ts = fmaf((float)(KSEL - s0), base - (float)k,
                                  wexcl + wpre[k]);
                }
            }
            ts = wave_bcast63_f(wave_scan_f(ts));

            float dd = red[p][0][0] + red[p][1][0] + red[p][2][0] + red[p][3][0];
            float nn = red[p][0][1] + red[p][1][1] + red[p][2][1] + red[p][3][1];

            const float topk_mean = ts * (1.0f / (64.0f * KSEL));
            const float cosv = dd * __builtin_amdgcn_rsqf(fmaxf(nn, 1e-24f));
            const float yt = sigma * topk_mean;
            const float et = __expf(-2.0f * yt);
            const float th = (1.0f - et) * __builtin_amdgcn_rcpf(1.0f + et);
            const float gate = __expf(-tau * cosv) * fmaf(w, th, 1.0f);
            if (lane == 0) gate_sh[p] = gate;
        } else {
            // idle waves rezero the OTHER parity buffer for row r+1
            if (t - 64 < NBINS / 4) {      // waves 1-3: 128 i4-stores cover 512 ints
                ((i4*)&hist[p ^ 1][0])[t - 64] = (i4)0;
            }
        }
        __syncthreads();                   // B2: gate + rezero visible

        const float gate = gate_sh[p];
        f4 oa, ob;
        oa.x = g[0]*gate; oa.y = g[1]*gate; oa.z = g[2]*gate; oa.w = g[3]*gate;
        ob.x = g[4]*gate; ob.y = g[5]*gate; ob.z = g[6]*gate; ob.w = g[7]*gate;
        f4* outr = (f4*)(out + (row0 + r) * D);
        outr[t]      = oa;
        outr[t + NT] = ob;
    }
}

extern "C" void kernel_launch(void* const* d_in, const int* in_sizes, int n_in,
                              void* d_out, int out_size, void* d_ws, size_t ws_size,
                              hipStream_t stream) {
    (void)n_in; (void)out_size; (void)d_ws; (void)ws_size;
    const float* x         = (const float*)d_in[0];
    const float* ema_mean  = (const float*)d_in[1];
    const float* ema_sq    = (const float*)d_in[2];
    const float* ema_out   = (const float*)d_in[3];
    const float* log_tau   = (const float*)d_in[4];
    const float* log_sigma = (const float*)d_in[5];
    const float* log_w     = (const float*)d_in[6];
    float* out = (float*)d_out;

    const int rows = in_sizes[0] / D;   // B*T = 16384
    row_kernel<<<rows / ROWS, NT, 0, stream>>>(x, ema_mean, ema_sq, ema_out,
                                               log_tau, log_sigma, log_w, out);
}

// Round 15
// 45.517 us; speedup vs baseline: 2.0451x; 1.0419x over previous
//
#include <hip/hip_runtime.h>
#include <math.h>

#define D      2048
#define KSEL   256
#define NT     256          // threads per block; NT*8 == D
#define NBINS  512          // bins of width 1/64 over |z| in [0,8)
#define ROWS   2            // rows per block; disjoint hist/red per row

typedef float f4 __attribute__((ext_vector_type(4)));
typedef int   i4 __attribute__((ext_vector_type(4)));

// tanh-form GELU: x * sigmoid(1.5957691*x + 0.0713548*x^3)
__device__ __forceinline__ float fast_gelu(float x) {
    float x2 = x * x;
    float t  = fmaf(x2, -0.0713548162f, -1.5957691216f);
    float e  = __expf(x * t);
    return x * __builtin_amdgcn_rcpf(1.0f + e);
}

// ---- DPP cross-lane (VALU pipe, no LDS) ----
template<int CTRL, int RMASK>
__device__ __forceinline__ float dpp_mov_f(float v) {
    int r = __builtin_amdgcn_update_dpp(0, __builtin_bit_cast(int, v),
                                        CTRL, RMASK, 0xf, true);
    return __builtin_bit_cast(float, r);
}
template<int CTRL, int RMASK>
__device__ __forceinline__ int dpp_mov_i(int v) {
    return __builtin_amdgcn_update_dpp(0, v, CTRL, RMASK, 0xf, true);
}
// inclusive prefix-sum across 64 lanes; lane 63 ends with the wave total
__device__ __forceinline__ float wave_scan_f(float x) {
    x += dpp_mov_f<0x111, 0xf>(x);   // row_shr:1
    x += dpp_mov_f<0x112, 0xf>(x);   // row_shr:2
    x += dpp_mov_f<0x114, 0xf>(x);   // row_shr:4
    x += dpp_mov_f<0x118, 0xf>(x);   // row_shr:8
    x += dpp_mov_f<0x142, 0xa>(x);   // row_bcast:15 -> rows 1,3
    x += dpp_mov_f<0x143, 0xc>(x);   // row_bcast:31 -> rows 2,3
    return x;
}
__device__ __forceinline__ int wave_scan_i(int x) {
    x += dpp_mov_i<0x111, 0xf>(x);
    x += dpp_mov_i<0x112, 0xf>(x);
    x += dpp_mov_i<0x114, 0xf>(x);
    x += dpp_mov_i<0x118, 0xf>(x);
    x += dpp_mov_i<0x142, 0xa>(x);
    x += dpp_mov_i<0x143, 0xc>(x);
    return x;
}
__device__ __forceinline__ float wave_bcast63_f(float x) {
    int r = __builtin_amdgcn_readlane(__builtin_bit_cast(int, x), 63);
    return __builtin_bit_cast(float, r);
}

// Fused; ONE barrier per row (+B0, +final); stores deferred one row.
__global__ __launch_bounds__(NT) void row_kernel(
    const float* __restrict__ x,
    const float* __restrict__ ema_mean,
    const float* __restrict__ ema_sq,
    const float* __restrict__ ema_out,
    const float* __restrict__ p_log_tau,
    const float* __restrict__ p_log_sigma,
    const float* __restrict__ p_log_w,
    float* __restrict__ out)
{
    __shared__ int   hist[ROWS][NBINS];   // one buffer per row, REVERSED idx
    __shared__ float ssred[4];
    __shared__ float red[ROWS][4][2];     // per-row dot/nrm partials
    __shared__ float gate_sh[ROWS];

    const int t    = threadIdx.x;
    const int wave = t >> 6;
    const int lane = t & 63;

    // scalar gate params (uniform; cheap redundant compute per block)
    const float tau   = __expf(p_log_tau[0]);
    const float sigma = __logf(1.0f + __expf(p_log_sigma[0])) + 0.01f;
    const float w     = __logf(1.0f + __expf(p_log_w[0]));

    // ---- inline "prep": per-thread channel constants (once per block) ----
    f4 m0 = ((const f4*)ema_mean)[t];
    f4 m1 = ((const f4*)ema_mean)[t + NT];
    f4 q0 = ((const f4*)ema_sq)[t];
    f4 q1 = ((const f4*)ema_sq)[t + NT];
    f4 e0 = ((const f4*)ema_out)[t];
    f4 e1 = ((const f4*)ema_out)[t + NT];

    const float mv[8] = {m0.x,m0.y,m0.z,m0.w, m1.x,m1.y,m1.z,m1.w};
    const float qv[8] = {q0.x,q0.y,q0.z,q0.w, q1.x,q1.y,q1.z,q1.w};
    const float ev[8] = {e0.x,e0.y,e0.z,e0.w, e1.x,e1.y,e1.z,e1.w};

    float a_[8], b_[8];
    float ss = 0.f;
#pragma unroll
    for (int j = 0; j < 8; ++j) {
        float v = fmaxf(fmaf(-mv[j], mv[j], qv[j]), 1e-6f);
        a_[j] = 64.0f * __builtin_amdgcn_rsqf(v);     // 64/std
        b_[j] = -mv[j] * a_[j];
        ss = fmaf(ev[j], ev[j], ss);
    }
    ss = wave_scan_f(ss);
    if (lane == 63) ssred[wave] = ss;

    const size_t row0 = (size_t)blockIdx.x * ROWS;
    f4 xa = ((const f4*)(x + row0 * D))[t];
    f4 xb = ((const f4*)(x + row0 * D))[t + NT];

    hist[0][t] = 0;  hist[0][t + NT] = 0;
    hist[1][t] = 0;  hist[1][t + NT] = 0;
    __syncthreads();                       // B0: zeros + ssred visible

    const float inv_nrm =
        1.0f / (sqrtf(ssred[0] + ssred[1] + ssred[2] + ssred[3]) + 1e-8f);
    float u_[8];
#pragma unroll
    for (int j = 0; j < 8; ++j) u_[j] = ev[j] * inv_nrm;

    float gprev[8];                        // previous row's gelu values

#pragma unroll
    for (int r = 0; r < ROWS; ++r) {
        const float xv[8] = {xa.x,xa.y,xa.z,xa.w, xb.x,xb.y,xb.z,xb.w};

        float g[8], av[8];
        float dot = 0.f, nrm = 0.f;
#pragma unroll
        for (int j = 0; j < 8; ++j) {
            float gg = fast_gelu(xv[j]);
            g[j] = gg;
            av[j] = fabsf(fmaf(xv[j], a_[j], b_[j]));   // 64*|z|
            dot = fmaf(gg, u_[j], dot);
            nrm = fmaf(gg, gg, nrm);
        }

        // prefetch next row's x
        if (r + 1 < ROWS) {
            const float* xn = x + (row0 + r + 1) * D;
            xa = ((const f4*)xn)[t];
            xb = ((const f4*)xn)[t + NT];
        }

        // cross-lane reduce dot/nrm on VALU; overlaps DS atomics below
        dot = wave_scan_f(dot);
        nrm = wave_scan_f(nrm);
        if (lane == 63) { red[r][wave][0] = dot; red[r][wave][1] = nrm; }

        // reversed-bin histogram into this row's buffer
#pragma unroll
        for (int j = 0; j < 8; ++j) {
            int bin = (int)av[j];
            bin = bin > NBINS - 1 ? NBINS - 1 : bin;
            atomicAdd(&hist[r][(NBINS - 1) - bin], 1);
        }
        __syncthreads();     // B1(r): hist[r]+red[r] ready; gate(r-1) visible

        // ---- deferred store of row r-1 (gate published before this barrier)
        if (r > 0) {
            const float gate = gate_sh[r - 1];
            f4 oa, ob;
            oa.x = gprev[0]*gate; oa.y = gprev[1]*gate;
            oa.z = gprev[2]*gate; oa.w = gprev[3]*gate;
            ob.x = gprev[4]*gate; ob.y = gprev[5]*gate;
            ob.z = gprev[6]*gate; ob.w = gprev[7]*gate;
            f4* outr = (f4*)(out + (row0 + r - 1) * D);
            outr[t]      = oa;
            outr[t + NT] = ob;
        }
#pragma unroll
        for (int j = 0; j < 8; ++j) gprev[j] = g[j];

        // ---- wave0: weighted scan -> topk_sum -> gate(r) (no extra barrier)
        if (wave == 0) {
            i4 va = *(const i4*)&hist[r][8 * lane];
            i4 vb = *(const i4*)&hist[r][8 * lane + 4];
            const float base = 511.5f - (float)(8 * lane);
            int c0 = va.x;
            int c1 = c0 + va.y;
            int c2 = c1 + va.z;
            int c3 = c2 + va.w;
            int c4 = c3 + vb.x;
            int c5 = c4 + vb.y;
            int c6 = c5 + vb.z;
            int c7 = c6 + vb.w;
            float w0 = (float)va.x * base;
            float w1 = fmaf((float)va.y, base - 1.0f, w0);
            float w2 = fmaf((float)va.z, base - 2.0f, w1);
            float w3 = fmaf((float)va.w, base - 3.0f, w2);
            float w4 = fmaf((float)vb.x, base - 4.0f, w3);
            float w5 = fmaf((float)vb.y, base - 5.0f, w4);
            float w6 = fmaf((float)vb.z, base - 6.0f, w5);
            float w7 = fmaf((float)vb.w, base - 7.0f, w6);

            int   incl  = wave_scan_i(c7);
            int   excl  = incl - c7;       // counts in (value-)higher bins
            float winc  = wave_scan_f(w7);
            float wexcl = winc - w7;       // their midpoint-weighted sum

            float ts = 0.f;
            {
                const int   pre[8]  = {0, c0, c1, c2, c3, c4, c5, c6};
                const int   cum[8]  = {c0, c1, c2, c3, c4, c5, c6, c7};
                const float wpre[8] = {0.f, w0, w1, w2, w3, w4, w5, w6};
#pragma unroll
                for (int k = 0; k < 8; ++k) {
                    int s0  = excl + pre[k];
                    int e0x = excl + cum[k];
                    if (s0 < KSEL && e0x >= KSEL)   // exactly one lane/k fires
                        ts = fmaf((float)(KSEL - s0), base - (float)k,
                                  wexcl + wpre[k]);
                }
            }
            ts = wave_bcast63_f(wave_scan_f(ts));

            float dd = red[r][0][0] + red[r][1][0] + red[r][2][0] + red[r][3][0];
            float nn = red[r][0][1] + red[r][1][1] + red[r][2][1] + red[r][3][1];

            const float topk_mean = ts * (1.0f / (64.0f * KSEL));
            const float cosv = dd * __builtin_amdgcn_rsqf(fmaxf(nn, 1e-24f));
            const float yt = sigma * topk_mean;
            const float et = __expf(-2.0f * yt);
            const float th = (1.0f - et) * __builtin_amdgcn_rcpf(1.0f + et);
            const float gate = __expf(-tau * cosv) * fmaf(w, th, 1.0f);
            if (lane == 0) gate_sh[r] = gate;
        }
    }

    __syncthreads();                       // final: last row's gate visible
    {
        const float gate = gate_sh[ROWS - 1];
        f4 oa, ob;
        oa.x = gprev[0]*gate; oa.y = gprev[1]*gate;
        oa.z = gprev[2]*gate; oa.w = gprev[3]*gate;
        ob.x = gprev[4]*gate; ob.y = gprev[5]*gate;
        ob.z = gprev[6]*gate; ob.w = gprev[7]*gate;
        f4* outr = (f4*)(out + (row0 + ROWS - 1) * D);
        outr[t]      = oa;
        outr[t + NT] = ob;
    }
}

extern "C" void kernel_launch(void* const* d_in, const int* in_sizes, int n_in,
                              void* d_out, int out_size, void* d_ws, size_t ws_size,
                              hipStream_t stream) {
    (void)n_in; (void)out_size; (void)d_ws; (void)ws_size;
    const float* x         = (const float*)d_in[0];
    const float* ema_mean  = (const float*)d_in[1];
    const float* ema_sq    = (const float*)d_in[2];
    const float* ema_out   = (const float*)d_in[3];
    const float* log_tau   = (const float*)d_in[4];
    const float* log_sigma = (const float*)d_in[5];
    const float* log_w     = (const float*)d_in[6];
    float* out = (float*)d_out;

    const int rows = in_sizes[0] / D;   // B*T = 16384
    row_kernel<<<rows / ROWS, NT, 0, stream>>>(x, ema_mean, ema_sq, ema_out,
                                               log_tau, log_sigma, log_w, out);
}

// Round 16
// 45.307 us; speedup vs baseline: 2.0545x; 1.0046x over previous
//
#include <hip/hip_runtime.h>
#include <math.h>

#define D      2048
#define KSEL   256
#define NT     256          // threads per block; NT*8 == D
#define NBINS  512          // bins of width 1/64 over |z| in [0,8)

typedef float f4 __attribute__((ext_vector_type(4)));
typedef int   i4 __attribute__((ext_vector_type(4)));

// tanh-form GELU: x * sigmoid(1.5957691*x + 0.0713548*x^3)
__device__ __forceinline__ float fast_gelu(float x) {
    float x2 = x * x;
    float t  = fmaf(x2, -0.0713548162f, -1.5957691216f);
    float e  = __expf(x * t);
    return x * __builtin_amdgcn_rcpf(1.0f + e);
}

// ---- DPP cross-lane (VALU pipe, no LDS) ----
template<int CTRL, int RMASK>
__device__ __forceinline__ float dpp_mov_f(float v) {
    int r = __builtin_amdgcn_update_dpp(0, __builtin_bit_cast(int, v),
                                        CTRL, RMASK, 0xf, true);
    return __builtin_bit_cast(float, r);
}
template<int CTRL, int RMASK>
__device__ __forceinline__ int dpp_mov_i(int v) {
    return __builtin_amdgcn_update_dpp(0, v, CTRL, RMASK, 0xf, true);
}
// inclusive prefix-sum across 64 lanes; lane 63 ends with the wave total
__device__ __forceinline__ float wave_scan_f(float x) {
    x += dpp_mov_f<0x111, 0xf>(x);   // row_shr:1
    x += dpp_mov_f<0x112, 0xf>(x);   // row_shr:2
    x += dpp_mov_f<0x114, 0xf>(x);   // row_shr:4
    x += dpp_mov_f<0x118, 0xf>(x);   // row_shr:8
    x += dpp_mov_f<0x142, 0xa>(x);   // row_bcast:15 -> rows 1,3
    x += dpp_mov_f<0x143, 0xc>(x);   // row_bcast:31 -> rows 2,3
    return x;
}
__device__ __forceinline__ int wave_scan_i(int x) {
    x += dpp_mov_i<0x111, 0xf>(x);
    x += dpp_mov_i<0x112, 0xf>(x);
    x += dpp_mov_i<0x114, 0xf>(x);
    x += dpp_mov_i<0x118, 0xf>(x);
    x += dpp_mov_i<0x142, 0xa>(x);
    x += dpp_mov_i<0x143, 0xc>(x);
    return x;
}
__device__ __forceinline__ float wave_bcast63_f(float x) {
    int r = __builtin_amdgcn_readlane(__builtin_bit_cast(int, x), 63);
    return __builtin_bit_cast(float, r);
}

// Computes gate for hist[which]; returns via gate_sh[which] (lane 0 writes).
__device__ __forceinline__ void scan_and_gate(
    const int* __restrict__ hh, int lane, float tau, float sigma, float w,
    const float dd, const float nn, float* gate_out)
{
    i4 va = *(const i4*)&hh[8 * lane];
    i4 vb = *(const i4*)&hh[8 * lane + 4];
    const float base = 511.5f - (float)(8 * lane);
    int c0 = va.x;
    int c1 = c0 + va.y;
    int c2 = c1 + va.z;
    int c3 = c2 + va.w;
    int c4 = c3 + vb.x;
    int c5 = c4 + vb.y;
    int c6 = c5 + vb.z;
    int c7 = c6 + vb.w;
    float w0 = (float)va.x * base;
    float w1 = fmaf((float)va.y, base - 1.0f, w0);
    float w2 = fmaf((float)va.z, base - 2.0f, w1);
    float w3 = fmaf((float)va.w, base - 3.0f, w2);
    float w4 = fmaf((float)vb.x, base - 4.0f, w3);
    float w5 = fmaf((float)vb.y, base - 5.0f, w4);
    float w6 = fmaf((float)vb.z, base - 6.0f, w5);
    float w7 = fmaf((float)vb.w, base - 7.0f, w6);

    int   incl  = wave_scan_i(c7);
    int   excl  = incl - c7;           // counts in (value-)higher bins
    float winc  = wave_scan_f(w7);
    float wexcl = winc - w7;           // their midpoint-weighted sum

    float ts = 0.f;
    {
        const int   pre[8]  = {0, c0, c1, c2, c3, c4, c5, c6};
        const int   cum[8]  = {c0, c1, c2, c3, c4, c5, c6, c7};
        const float wpre[8] = {0.f, w0, w1, w2, w3, w4, w5, w6};
#pragma unroll
        for (int k = 0; k < 8; ++k) {
            int s0  = excl + pre[k];
            int e0x = excl + cum[k];
            if (s0 < KSEL && e0x >= KSEL)   // exactly one lane/k fires
                ts = fmaf((float)(KSEL - s0), base - (float)k,
                          wexcl + wpre[k]);
        }
    }
    ts = wave_bcast63_f(wave_scan_f(ts));

    const float topk_mean = ts * (1.0f / (64.0f * KSEL));
    const float cosv = dd * __builtin_amdgcn_rsqf(fmaxf(nn, 1e-24f));
    const float yt = sigma * topk_mean;
    const float et = __expf(-2.0f * yt);
    const float th = (1.0f - et) * __builtin_amdgcn_rcpf(1.0f + et);  // tanh
    const float gate = __expf(-tau * cosv) * fmaf(w, th, 1.0f);
    if (lane == 0) *gate_out = gate;
}

// Two rows per block, processed CONCURRENTLY; 3 barriers total.
__global__ __launch_bounds__(NT) void row_kernel(
    const float* __restrict__ x,
    const float* __restrict__ ema_mean,
    const float* __restrict__ ema_sq,
    const float* __restrict__ ema_out,
    const float* __restrict__ p_log_tau,
    const float* __restrict__ p_log_sigma,
    const float* __restrict__ p_log_w,
    float* __restrict__ out)
{
    __shared__ int   hist[2][NBINS];      // one buffer per row, REVERSED idx
    __shared__ float ssred[4];
    __shared__ float red[2][4][2];        // per-row dot/nrm partials
    __shared__ float gate_sh[2];

    const int t    = threadIdx.x;
    const int wave = t >> 6;
    const int lane = t & 63;

    const float tau   = __expf(p_log_tau[0]);
    const float sigma = __logf(1.0f + __expf(p_log_sigma[0])) + 0.01f;
    const float w     = __logf(1.0f + __expf(p_log_w[0]));

    // ---- channel constants ----
    f4 m0 = ((const f4*)ema_mean)[t];
    f4 m1 = ((const f4*)ema_mean)[t + NT];
    f4 q0 = ((const f4*)ema_sq)[t];
    f4 q1 = ((const f4*)ema_sq)[t + NT];
    f4 e0 = ((const f4*)ema_out)[t];
    f4 e1 = ((const f4*)ema_out)[t + NT];

    // both rows' x issued immediately (max memory-level parallelism)
    const size_t row0 = (size_t)blockIdx.x * 2;
    f4 xa0 = ((const f4*)(x + row0 * D))[t];
    f4 xb0 = ((const f4*)(x + row0 * D))[t + NT];
    f4 xa1 = ((const f4*)(x + (row0 + 1) * D))[t];
    f4 xb1 = ((const f4*)(x + (row0 + 1) * D))[t + NT];

    const float mv[8] = {m0.x,m0.y,m0.z,m0.w, m1.x,m1.y,m1.z,m1.w};
    const float qv[8] = {q0.x,q0.y,q0.z,q0.w, q1.x,q1.y,q1.z,q1.w};
    const float ev[8] = {e0.x,e0.y,e0.z,e0.w, e1.x,e1.y,e1.z,e1.w};

    float a_[8], b_[8];
    float ss = 0.f;
#pragma unroll
    for (int j = 0; j < 8; ++j) {
        float v = fmaxf(fmaf(-mv[j], mv[j], qv[j]), 1e-6f);
        a_[j] = 64.0f * __builtin_amdgcn_rsqf(v);     // 64/std
        b_[j] = -mv[j] * a_[j];
        ss = fmaf(ev[j], ev[j], ss);
    }
    ss = wave_scan_f(ss);
    if (lane == 63) ssred[wave] = ss;

    hist[0][t] = 0;  hist[0][t + NT] = 0;
    hist[1][t] = 0;  hist[1][t + NT] = 0;
    __syncthreads();                       // B0: zeros + ssred visible

    const float inv_nrm =
        1.0f / (sqrtf(ssred[0] + ssred[1] + ssred[2] + ssred[3]) + 1e-8f);
    float u_[8];
#pragma unroll
    for (int j = 0; j < 8; ++j) u_[j] = ev[j] * inv_nrm;

    // ---- elementwise: BOTH rows (independent chains -> ILP) ----
    const float xv0[8] = {xa0.x,xa0.y,xa0.z,xa0.w, xb0.x,xb0.y,xb0.z,xb0.w};
    const float xv1[8] = {xa1.x,xa1.y,xa1.z,xa1.w, xb1.x,xb1.y,xb1.z,xb1.w};

    float g0[8], g1[8], av0[8], av1[8];
    float dot0 = 0.f, nrm0 = 0.f, dot1 = 0.f, nrm1 = 0.f;
#pragma unroll
    for (int j = 0; j < 8; ++j) {
        float ga = fast_gelu(xv0[j]);
        float gb = fast_gelu(xv1[j]);
        g0[j] = ga;  g1[j] = gb;
        av0[j] = fabsf(fmaf(xv0[j], a_[j], b_[j]));
        av1[j] = fabsf(fmaf(xv1[j], a_[j], b_[j]));
        dot0 = fmaf(ga, u_[j], dot0);
        nrm0 = fmaf(ga, ga, nrm0);
        dot1 = fmaf(gb, u_[j], dot1);
        nrm1 = fmaf(gb, gb, nrm1);
    }

    dot0 = wave_scan_f(dot0);
    nrm0 = wave_scan_f(nrm0);
    dot1 = wave_scan_f(dot1);
    nrm1 = wave_scan_f(nrm1);
    if (lane == 63) {
        red[0][wave][0] = dot0; red[0][wave][1] = nrm0;
        red[1][wave][0] = dot1; red[1][wave][1] = nrm1;
    }

    // both rows' histograms (disjoint buffers)
#pragma unroll
    for (int j = 0; j < 8; ++j) {
        int b0 = (int)av0[j];  b0 = b0 > NBINS - 1 ? NBINS - 1 : b0;
        int b1 = (int)av1[j];  b1 = b1 > NBINS - 1 ? NBINS - 1 : b1;
        atomicAdd(&hist[0][(NBINS - 1) - b0], 1);
        atomicAdd(&hist[1][(NBINS - 1) - b1], 1);
    }
    __syncthreads();                       // B1: hists + red ready

    // wave0 -> row0 scan+gate; wave1 -> row1 (concurrent)
    if (wave == 0) {
        float dd = red[0][0][0] + red[0][1][0] + red[0][2][0] + red[0][3][0];
        float nn = red[0][0][1] + red[0][1][1] + red[0][2][1] + red[0][3][1];
        scan_and_gate(&hist[0][0], lane, tau, sigma, w, dd, nn, &gate_sh[0]);
    } else if (wave == 1) {
        float dd = red[1][0][0] + red[1][1][0] + red[1][2][0] + red[1][3][0];
        float nn = red[1][0][1] + red[1][1][1] + red[1][2][1] + red[1][3][1];
        scan_and_gate(&hist[1][0], lane, tau, sigma, w, dd, nn, &gate_sh[1]);
    }
    __syncthreads();                       // B2: gates visible

    // ---- store both rows in one streaming burst ----
    const float gateA = gate_sh[0];
    const float gateB = gate_sh[1];
    f4 oa, ob;
    oa.x = g0[0]*gateA; oa.y = g0[1]*gateA; oa.z = g0[2]*gateA; oa.w = g0[3]*gateA;
    ob.x = g0[4]*gateA; ob.y = g0[5]*gateA; ob.z = g0[6]*gateA; ob.w = g0[7]*gateA;
    f4* outr0 = (f4*)(out + row0 * D);
    outr0[t]      = oa;
    outr0[t + NT] = ob;
    oa.x = g1[0]*gateB; oa.y = g1[1]*gateB; oa.z = g1[2]*gateB; oa.w = g1[3]*gateB;
    ob.x = g1[4]*gateB; ob.y = g1[5]*gateB; ob.z = g1[6]*gateB; ob.w = g1[7]*gateB;
    f4* outr1 = (f4*)(out + (row0 + 1) * D);
    outr1[t]      = oa;
    outr1[t + NT] = ob;
}

extern "C" void kernel_launch(void* const* d_in, const int* in_sizes, int n_in,
                              void* d_out, int out_size, void* d_ws, size_t ws_size,
                              hipStream_t stream) {
    (void)n_in; (void)out_size; (void)d_ws; (void)ws_size;
    const float* x         = (const float*)d_in[0];
    const float* ema_mean  = (const float*)d_in[1];
    const float* ema_sq    = (const float*)d_in[2];
    const float* ema_out   = (const float*)d_in[3];
    const float* log_tau   = (const float*)d_in[4];
    const float* log_sigma = (const float*)d_in[5];
    const float* log_w     = (const float*)d_in[6];
    float* out = (float*)d_out;

    const int rows = in_sizes[0] / D;   // B*T = 16384
    row_kernel<<<rows / 2, NT, 0, stream>>>(x, ema_mean, ema_sq, ema_out,
                                            log_tau, log_sigma, log_w, out);
}